// Round 2
// baseline (459.096 us; speedup 1.0000x reference)
//
#include <hip/hip_runtime.h>

// PNN fused kernel for MI355X (gfx950), round 2.
//
// Structure: 256 blocks x 512 threads; block owns 64 rows.
// - Embeddings gathered in f-chunks of 8 (39 = 4x8 + 7) into double-buffered
//   LDS (2 x 32 KB), one 64B embedding row per thread per chunk (xv-scaled at
//   commit). Gather of chunk c+1 is issued before compute of chunk c.
// - Einsum: wave w owns 8 of the 64 outputs (waves 0-3 -> w_first d=8w..,
//   waves 4-7 -> w_inner). lane = row. acc[8] per lane (no spill). Weight
//   addresses are wave-uniform -> scalar loads; emb from LDS b128 reads with
//   32 FMA reuse each -> VALU-bound.
// - MLP fused at block tail, parallelized 512-wide (64 rows x 8 neuron
//   groups) with weights staged in LDS.

namespace {

constexpr int Bn = 16384;
constexpr int Fn = 39;
constexpr int Vn = 100000;
constexpr int En = 16;
constexpr int ROWS = 64;
constexpr int THREADS = 512;
constexpr int CF = 8;                 // f per full chunk
constexpr int NFULL = 4;              // chunks 0..3 have 8 f, chunk 4 has 7
constexpr int FVEC = CF * 4;          // float4 slots per row per chunk (32)

__device__ __forceinline__ void gather_chunk(
    const int* __restrict__ Xi, const float* __restrict__ Xv,
    const float* __restrict__ T, int row0, int c, int cf, int tid,
    float4 g[4], float& xv)
{
    if (tid < ROWS * cf) {
        const int r = tid & 63, fl = tid >> 6;
        const int f = c * CF + fl;
        const int b = row0 + r;
        const int idx = Xi[b * Fn + f];
        xv = Xv[b * Fn + f];
        const float4* src = reinterpret_cast<const float4*>(
            T + ((size_t)f * Vn + (size_t)idx) * En);
        g[0] = src[0]; g[1] = src[1]; g[2] = src[2]; g[3] = src[3];
    }
}

__device__ __forceinline__ void commit_chunk(
    float4* __restrict__ dst, int cf, int tid, const float4 g[4], float xv)
{
    if (tid < ROWS * cf) {
        const int r = tid & 63, fl = tid >> 6;
#pragma unroll
        for (int q = 0; q < 4; ++q) {
            float4 v = g[q];
            v.x *= xv; v.y *= xv; v.z *= xv; v.w *= xv;
            dst[(fl * 4 + q) * ROWS + r] = v;   // contiguous 1KB per wave-instr
        }
    }
}

template <int CFT>
__device__ __forceinline__ void compute_chunk(
    const float4* __restrict__ src, const float* __restrict__ wbase,
    int c, int lane, float acc[8])
{
#pragma unroll
    for (int fl = 0; fl < CFT; ++fl) {
        const int kb = (c * CF + fl) * En;
#pragma unroll
        for (int q = 0; q < 4; ++q) {
            const float4 e4 = src[(fl * 4 + q) * ROWS + lane];
#pragma unroll
            for (int d = 0; d < 8; ++d) {
                // wave-uniform address -> scalar load path
                const float4 w4 = *reinterpret_cast<const float4*>(
                    wbase + d * (Fn * En) + kb + q * 4);
                acc[d] = fmaf(e4.x, w4.x, acc[d]);
                acc[d] = fmaf(e4.y, w4.y, acc[d]);
                acc[d] = fmaf(e4.z, w4.z, acc[d]);
                acc[d] = fmaf(e4.w, w4.w, acc[d]);
            }
        }
    }
}

__global__ __launch_bounds__(THREADS) void pnn_fused(
    const int* __restrict__ Xi,
    const float* __restrict__ Xv,
    const float* __restrict__ T,
    const float* __restrict__ w_first,
    const float* __restrict__ w_inner,
    const float* __restrict__ lin1_W,
    const float* __restrict__ lin1_b,
    const float* __restrict__ lin2_W,
    const float* __restrict__ lin2_b,
    const float* __restrict__ last_W,
    const float* __restrict__ last_b,
    float* __restrict__ out)
{
    __shared__ float4 buf[2][FVEC * ROWS];   // 2 x 32 KB

    const int tid = threadIdx.x;
    const int lane = tid & 63;
    const int wv = __builtin_amdgcn_readfirstlane(tid >> 6);
    const int row0 = blockIdx.x * ROWS;

    // wave -> d slice: waves 0-3 w_first d=8wv.., waves 4-7 w_inner
    const float* wbase = ((wv < 4) ? w_first : w_inner) + (wv & 3) * 8 * (Fn * En);

    float acc[8];
#pragma unroll
    for (int d = 0; d < 8; ++d) acc[d] = 0.0f;

    float4 g[4] = {{0,0,0,0},{0,0,0,0},{0,0,0,0},{0,0,0,0}};
    float xv = 0.0f;

    // prologue: chunk 0 -> buf0
    gather_chunk(Xi, Xv, T, row0, 0, CF, tid, g, xv);
    commit_chunk(&buf[0][0], CF, tid, g, xv);
    __syncthreads();

    // chunks 0..3: gather next, compute current, commit next, barrier
    for (int c = 0; c < NFULL; ++c) {
        const int cfn = (c == NFULL - 1) ? 7 : CF;
        gather_chunk(Xi, Xv, T, row0, c + 1, cfn, tid, g, xv);
        compute_chunk<CF>(&buf[c & 1][0], wbase, c, lane, acc);
        commit_chunk(&buf[(c + 1) & 1][0], cfn, tid, g, xv);
        __syncthreads();
    }
    // final (ragged) chunk: in buf[0]
    compute_chunk<7>(&buf[0][0], wbase, NFULL, lane, acc);

    // x[d][row] into buf1 region (not read by chunk-4 compute)
    float* xt = reinterpret_cast<float*>(&buf[1][0]);
#pragma unroll
    for (int d = 0; d < 8; ++d) xt[(wv * 8 + d) * ROWS + lane] = acc[d];
    __syncthreads();   // chunk-4 reads of buf0 done; x visible

    // stage MLP weights into buf0 region
    float* wsh = reinterpret_cast<float*>(&buf[0][0]);
    for (int i = tid; i < 2048; i += THREADS)
        wsh[i] = (i < 1024) ? lin1_W[i] : lin2_W[i - 1024];
    if (tid < 32) {
        wsh[2048 + tid] = lin1_b[tid];
        wsh[2080 + tid] = lin2_b[tid];
        wsh[2112 + tid] = last_W[tid];
    }
    if (tid == 0) wsh[2144] = last_b[0];

    // xin[j*64+r] = first + s^2   (same flat layout as xt)
    float* xin = wsh + 2176;
    for (int p = tid; p < 2048; p += THREADS) {
        const float s = xt[2048 + p];
        xin[p] = xt[p] + s * s;
    }
    __syncthreads();

    // MLP layer 1: tid = r + 64*g, lane computes y1[g*4..g*4+4][r]
    float* y1 = wsh + 2176 + 2048;
    {
        const int r = tid & 63, gq = tid >> 6;
        float a0 = wsh[2048 + gq * 4 + 0];
        float a1 = wsh[2048 + gq * 4 + 1];
        float a2 = wsh[2048 + gq * 4 + 2];
        float a3 = wsh[2048 + gq * 4 + 3];
#pragma unroll
        for (int j = 0; j < 32; ++j) {
            const float xj = xin[j * 64 + r];           // conflict-free
            a0 = fmaf(wsh[(gq * 4 + 0) * 32 + j], xj, a0);   // broadcast
            a1 = fmaf(wsh[(gq * 4 + 1) * 32 + j], xj, a1);
            a2 = fmaf(wsh[(gq * 4 + 2) * 32 + j], xj, a2);
            a3 = fmaf(wsh[(gq * 4 + 3) * 32 + j], xj, a3);
        }
        y1[(gq * 4 + 0) * 64 + r] = fmaxf(a0, 0.0f);
        y1[(gq * 4 + 1) * 64 + r] = fmaxf(a1, 0.0f);
        y1[(gq * 4 + 2) * 64 + r] = fmaxf(a2, 0.0f);
        y1[(gq * 4 + 3) * 64 + r] = fmaxf(a3, 0.0f);
    }
    __syncthreads();

    // MLP layer 2: y1 -> y2 (y2 reuses xin region)
    float* y2 = xin;
    {
        const int r = tid & 63, gq = tid >> 6;
        float a0 = wsh[2080 + gq * 4 + 0];
        float a1 = wsh[2080 + gq * 4 + 1];
        float a2 = wsh[2080 + gq * 4 + 2];
        float a3 = wsh[2080 + gq * 4 + 3];
#pragma unroll
        for (int j = 0; j < 32; ++j) {
            const float xj = y1[j * 64 + r];
            a0 = fmaf(wsh[1024 + (gq * 4 + 0) * 32 + j], xj, a0);
            a1 = fmaf(wsh[1024 + (gq * 4 + 1) * 32 + j], xj, a1);
            a2 = fmaf(wsh[1024 + (gq * 4 + 2) * 32 + j], xj, a2);
            a3 = fmaf(wsh[1024 + (gq * 4 + 3) * 32 + j], xj, a3);
        }
        y2[(gq * 4 + 0) * 64 + r] = fmaxf(a0, 0.0f);
        y2[(gq * 4 + 1) * 64 + r] = fmaxf(a1, 0.0f);
        y2[(gq * 4 + 2) * 64 + r] = fmaxf(a2, 0.0f);
        y2[(gq * 4 + 3) * 64 + r] = fmaxf(a3, 0.0f);
    }
    __syncthreads();

    // last layer + row sum (output is scalar per row)
    if (tid < 64) {
        float res = wsh[2144];
#pragma unroll
        for (int j = 0; j < 32; ++j)
            res = fmaf(wsh[2112 + j], y2[j * 64 + tid], res);
        out[row0 + tid] = res;
    }
}

} // namespace

extern "C" void kernel_launch(void* const* d_in, const int* in_sizes, int n_in,
                              void* d_out, int out_size, void* d_ws, size_t ws_size,
                              hipStream_t stream) {
    const int*   Xi      = (const int*)d_in[0];
    const float* Xv      = (const float*)d_in[1];
    const float* T       = (const float*)d_in[2];
    const float* w_first = (const float*)d_in[3];
    const float* w_inner = (const float*)d_in[4];
    const float* lin1_W  = (const float*)d_in[5];
    const float* lin1_b  = (const float*)d_in[6];
    const float* lin2_W  = (const float*)d_in[7];
    const float* lin2_b  = (const float*)d_in[8];
    const float* last_W  = (const float*)d_in[9];
    const float* last_b  = (const float*)d_in[10];
    float* out = (float*)d_out;

    dim3 grid(Bn / ROWS);    // 256
    dim3 block(THREADS);     // 512
    hipLaunchKernelGGL(pnn_fused, grid, block, 0, stream,
                       Xi, Xv, T, w_first, w_inner,
                       lin1_W, lin1_b, lin2_W, lin2_b, last_W, last_b, out);
}

// Round 3
// 329.880 us; speedup vs baseline: 1.3917x; 1.3917x over previous
//
#include <hip/hip_runtime.h>

// PNN fused kernel for MI355X (gfx950), round 3.
//
// Single kernel, MFMA-based:
//  - Block owns M=32 rows, 512 threads (8 waves), grid = 512 -> 2 blocks/CU
//    resident (LDS 51.5 KB allows 3), 16 waves/CU during the gather phase.
//  - Phase 1: stage Xi/Xv coalesced into LDS; gather 32x39 embedding rows
//    (64 B random each), scale by Xv, convert f16, pack LDS A[32][648]
//    (row stride 648 halfs -> 2-way bank conflicts only; K-pad 624..647 zeroed).
//  - Phase 2: C[32x64] = A[32x624] x Wcat[624x64] via mfma_f32_16x16x32_f16.
//    Wave = (row-half q, col-tile t16): one 16x16 tile, 20 K-steps.
//    A-frag: ds_read_b128, layout A[m=lane&15][k=(lane>>4)*8+j].
//    B-frag: per-lane 8 contiguous fp32 from w_first/w_inner (k = f*16+e is
//    exactly the weight row layout), cvt to f16. k clamped at ragged tail
//    (A pad is zero there, so clamped B values contribute 0).
//    C/D layout: col=lane&15, row=(lane>>4)*4+reg (HW-verified mapping).
//  - Phase 3: x = first + s^2 -> fused 32->32->32->1 MLP in LDS (round-2
//    structure, fp32), out[b] per row.

namespace {

typedef _Float16 half8 __attribute__((ext_vector_type(8)));
typedef float floatx4 __attribute__((ext_vector_type(4)));

constexpr int Bn = 16384;
constexpr int Fn = 39;
constexpr int Vn = 100000;
constexpr int En = 16;
constexpr int M = 32;           // rows per block
constexpr int THREADS = 512;
constexpr int AST = 648;        // A row stride (halfs): 624 data + 24 pad
constexpr int KSTEPS = 20;      // ceil(624/32)

union SMem {
    struct {
        __align__(16) _Float16 A[M * AST];   // 41472 B
        __align__(16) int   xi[M * Fn];      // 4992 B
        __align__(16) float xv[M * Fn];      // 4992 B
    } g;                                     // 51456 B
    struct {
        float x[M * 69];     // 8832 B  (x[row][d], stride 69: conflict-free)
        float wsh[2176];     // lin1_W[0..1023] lin2_W[1024..2047] b1@2048 b2@2080 lastW@2112 lastb@2144
        float r1[1024];      // xin, later y2   [n*32 + r]
        float r2[1024];      // y1              [n*32 + r]
    } e;
};

__device__ __forceinline__ half8 cvt8s(float4 a, float4 b, float s) {
    half8 h;
    h[0] = (_Float16)(a.x * s); h[1] = (_Float16)(a.y * s);
    h[2] = (_Float16)(a.z * s); h[3] = (_Float16)(a.w * s);
    h[4] = (_Float16)(b.x * s); h[5] = (_Float16)(b.y * s);
    h[6] = (_Float16)(b.z * s); h[7] = (_Float16)(b.w * s);
    return h;
}

__device__ __forceinline__ half8 cvt8(float4 a, float4 b) {
    half8 h;
    h[0] = (_Float16)a.x; h[1] = (_Float16)a.y;
    h[2] = (_Float16)a.z; h[3] = (_Float16)a.w;
    h[4] = (_Float16)b.x; h[5] = (_Float16)b.y;
    h[6] = (_Float16)b.z; h[7] = (_Float16)b.w;
    return h;
}

__global__ __launch_bounds__(THREADS, 6) void pnn_main(
    const int* __restrict__ Xi,
    const float* __restrict__ Xv,
    const float* __restrict__ T,
    const float* __restrict__ w_first,
    const float* __restrict__ w_inner,
    const float* __restrict__ lin1_W,
    const float* __restrict__ lin1_b,
    const float* __restrict__ lin2_W,
    const float* __restrict__ lin2_b,
    const float* __restrict__ last_W,
    const float* __restrict__ last_b,
    float* __restrict__ out)
{
    __shared__ SMem sm;

    const int tid = threadIdx.x;
    const int lane = tid & 63;
    const int wv = tid >> 6;
    const int row0 = blockIdx.x * M;

    // ---- stage Xi/Xv (coalesced 16B) + zero A K-pad ----
    if (tid < (M * Fn) / 4) {   // 312
        reinterpret_cast<int4*>(sm.g.xi)[tid] =
            reinterpret_cast<const int4*>(Xi + (size_t)row0 * Fn)[tid];
        reinterpret_cast<float4*>(sm.g.xv)[tid] =
            reinterpret_cast<const float4*>(Xv + (size_t)row0 * Fn)[tid];
    }
    if (tid < M * 4) {          // zero cols 624..647 of each row (3 x 16B)
        const int r = tid >> 2, c3 = tid & 3;
        if (c3 < 3) {
            float4 z = {0.0f, 0.0f, 0.0f, 0.0f};
            *reinterpret_cast<float4*>(&sm.g.A[r * AST + 624 + c3 * 8]) = z;
        }
    }
    __syncthreads();

    // ---- gather: 1248 random 64B rows -> scaled f16 A-tile ----
    for (int base = 0; base < M * Fn; base += THREADS) {
        const int i = base + tid;
        if (i < M * Fn) {
            const int r = i & 31, f = i >> 5;
            const int idx = sm.g.xi[r * Fn + f];
            const float s = sm.g.xv[r * Fn + f];
            const float4* src = reinterpret_cast<const float4*>(
                T + ((size_t)f * Vn + (size_t)idx) * En);
            const float4 q0 = src[0], q1 = src[1], q2 = src[2], q3 = src[3];
            *reinterpret_cast<half8*>(&sm.g.A[r * AST + f * 16])     = cvt8s(q0, q1, s);
            *reinterpret_cast<half8*>(&sm.g.A[r * AST + f * 16 + 8]) = cvt8s(q2, q3, s);
        }
    }
    __syncthreads();

    // ---- MFMA: wave = (q = row-half, t16 = col-tile 0..3) ----
    const int q = wv & 1;
    const int t16 = wv >> 1;
    const int m = lane & 15;
    const int g8 = (lane >> 4) * 8;
    // col-tiles 0,1 -> w_first rows 0..31; tiles 2,3 -> w_inner rows 0..31
    const float* wsrc = ((t16 < 2) ? w_first : w_inner)
                        + (size_t)((t16 & 1) * 16 + m) * (Fn * En);
    const _Float16* arow = &sm.g.A[(q * 16 + m) * AST + g8];

    floatx4 acc = {0.0f, 0.0f, 0.0f, 0.0f};
#pragma unroll
    for (int t = 0; t < KSTEPS; ++t) {
        const half8 af = *reinterpret_cast<const half8*>(arow + t * 32);
        int kb = t * 32 + g8;
        kb = (kb > 616) ? 616 : kb;   // ragged tail: A is zero there anyway
        const float4 w0 = *reinterpret_cast<const float4*>(wsrc + kb);
        const float4 w1 = *reinterpret_cast<const float4*>(wsrc + kb + 4);
        acc = __builtin_amdgcn_mfma_f32_16x16x32_f16(af, cvt8(w0, w1), acc, 0, 0, 0);
    }
    __syncthreads();   // all A reads done; safe to overlay epilogue regions

    // ---- write C tile: col=lane&15, row=(lane>>4)*4+reg ----
    {
        const int col = t16 * 16 + m;
        const int rbase = q * 16 + (lane >> 4) * 4;
#pragma unroll
        for (int r = 0; r < 4; ++r)
            sm.e.x[(rbase + r) * 69 + col] = acc[r];
    }

    // ---- stage MLP weights ----
    for (int i = tid; i < 2145; i += THREADS) {
        float v;
        if (i < 1024)      v = lin1_W[i];
        else if (i < 2048) v = lin2_W[i - 1024];
        else if (i < 2080) v = lin1_b[i - 2048];
        else if (i < 2112) v = lin2_b[i - 2080];
        else if (i < 2144) v = last_W[i - 2112];
        else               v = last_b[0];
        sm.e.wsh[i] = v;
    }
    __syncthreads();

    // ---- xin[j][r] = first + s^2 ----
    for (int p = tid; p < 1024; p += THREADS) {
        const int j = p >> 5, r = p & 31;
        const float fi = sm.e.x[r * 69 + j];
        const float s  = sm.e.x[r * 69 + 32 + j];
        sm.e.r1[j * 32 + r] = fi + s * s;
    }
    __syncthreads();

    // ---- layer 1: r1 -> r2 ----
    {
        const int r = tid & 31, n0 = (tid >> 5) * 2;
        float a0 = sm.e.wsh[2048 + n0];
        float a1 = sm.e.wsh[2048 + n0 + 1];
#pragma unroll
        for (int j = 0; j < 32; ++j) {
            const float xj = sm.e.r1[j * 32 + r];
            a0 = fmaf(sm.e.wsh[n0 * 32 + j],       xj, a0);
            a1 = fmaf(sm.e.wsh[(n0 + 1) * 32 + j], xj, a1);
        }
        sm.e.r2[n0 * 32 + r]       = fmaxf(a0, 0.0f);
        sm.e.r2[(n0 + 1) * 32 + r] = fmaxf(a1, 0.0f);
    }
    __syncthreads();

    // ---- layer 2: r2 -> r1 ----
    {
        const int r = tid & 31, n0 = (tid >> 5) * 2;
        float a0 = sm.e.wsh[2080 + n0];
        float a1 = sm.e.wsh[2080 + n0 + 1];
#pragma unroll
        for (int j = 0; j < 32; ++j) {
            const float xj = sm.e.r2[j * 32 + r];
            a0 = fmaf(sm.e.wsh[1024 + n0 * 32 + j],       xj, a0);
            a1 = fmaf(sm.e.wsh[1024 + (n0 + 1) * 32 + j], xj, a1);
        }
        sm.e.r1[n0 * 32 + r]       = fmaxf(a0, 0.0f);
        sm.e.r1[(n0 + 1) * 32 + r] = fmaxf(a1, 0.0f);
    }
    __syncthreads();

    // ---- last layer + store ----
    if (tid < M) {
        float res = sm.e.wsh[2144];
#pragma unroll
        for (int j = 0; j < 32; ++j)
            res = fmaf(sm.e.wsh[2112 + j], sm.e.r1[j * 32 + tid], res);
        out[row0 + tid] = res;
    }
}

} // namespace

extern "C" void kernel_launch(void* const* d_in, const int* in_sizes, int n_in,
                              void* d_out, int out_size, void* d_ws, size_t ws_size,
                              hipStream_t stream) {
    (void)d_ws; (void)ws_size; (void)in_sizes; (void)n_in; (void)out_size;
    const int*   Xi      = (const int*)d_in[0];
    const float* Xv      = (const float*)d_in[1];
    const float* T       = (const float*)d_in[2];
    const float* w_first = (const float*)d_in[3];
    const float* w_inner = (const float*)d_in[4];
    const float* lin1_W  = (const float*)d_in[5];
    const float* lin1_b  = (const float*)d_in[6];
    const float* lin2_W  = (const float*)d_in[7];
    const float* lin2_b  = (const float*)d_in[8];
    const float* last_W  = (const float*)d_in[9];
    const float* last_b  = (const float*)d_in[10];
    float* out = (float*)d_out;

    dim3 grid(Bn / M);       // 512 blocks
    dim3 block(THREADS);     // 512 threads = 8 waves
    hipLaunchKernelGGL(pnn_main, grid, block, 0, stream,
                       Xi, Xv, T, w_first, w_inner,
                       lin1_W, lin1_b, lin2_W, lin2_b, last_W, last_b, out);
}